// Round 8
// baseline (433.231 us; speedup 1.0000x reference)
//
#include <hip/hip_runtime.h>

namespace {
constexpr int T = 20;
constexpr int CINc = 32;
constexpr int COUTc = 64;
constexpr int HWc = 64;
constexpr int IMG = CINc * HWc * HWc;            // 131072
constexpr int OHW = 32;
constexpr int PLANE = OHW * OHW;                 // 1024
constexpr int SPIKE_SZ = 8 * T * COUTc * PLANE;  // 10485760
constexpr int CNT_SZ = 8 * COUTc * PLANE;        // 524288
constexpr int W_ELEMS = 9 * COUTc * CINc;        // 18432 per (set, hi/lo)
constexpr float LO_SCALE = 16777216.0f;          // 2^24
constexpr float LO_INV = 5.9604644775390625e-8f; // 2^-24
constexpr int CGRP = 3168;                       // ushorts per ci-group plane (6*66*8)
}

typedef _Float16 half8 __attribute__((ext_vector_type(8)));
typedef float f32x4 __attribute__((ext_vector_type(4)));

__device__ __forceinline__ unsigned short h_bits(_Float16 h) {
  return __builtin_bit_cast(unsigned short, h);
}

// Precompute BN-folded weights in MFMA B-fragment layout, fp16 split:
// w = H + L*2^-24 (L = fp16((w-H)*2^24)).
// ws ushort layout: [set(spike=0,ann=1)][hi=0,lo=1][tap][cout][cin]
__global__ void wprep_kernel(const float* __restrict__ w,
                             const float* __restrict__ gamma,
                             const float* __restrict__ rv,
                             unsigned short* __restrict__ ws) {
  int idx = blockIdx.x * 256 + threadIdx.x;
  if (idx >= 2 * W_ELEMS) return;
  int ci = idx & 31;
  int co = (idx >> 5) & 63;
  int v = idx >> 11;            // 0..17
  int tap = v % 9;
  int set = v / 9;
  float denom = set ? sqrtf(rv[co] + 1e-5f) : sqrtf(rv[co]);
  float val = w[(co * 32 + ci) * 9 + tap] * (gamma[co] / denom);
  _Float16 h = (_Float16)val;
  _Float16 l = (_Float16)((val - (float)h) * LO_SCALE);
  int base = set * (2 * W_ELEMS) + (tap * 64 + co) * 32 + ci;
  ws[base] = h_bits(h);
  ws[base + W_ELEMS] = h_bits(l);
}

// Conv 3x3 pad1 (implicit GEMM via fp16-split MFMA) + BN-fold + 2x2 maxpool.
// Block: 4 conv rows x 64 cols x 64 couts. 4 waves: wave = 2 conv rows x 32 couts,
// computed as two sequential 16-cout halves (j-split) so acc = 64 regs.
// LDS layout is ci-group-major: [c(=ci/8)][pixel(6*66)][8 ci] so A-fragment
// ds_read_b128 runs at 16B lane stride = bank-conflict-free, with a single
// lane base register + compile-time immediate offsets (the R4 discipline).
__global__ __launch_bounds__(256, 2)
void conv_mfma_kernel(const float* __restrict__ x_st,
                      const float* __restrict__ x_sc,
                      const float* __restrict__ b,
                      const float* __restrict__ gamma,
                      const float* __restrict__ beta,
                      const float* __restrict__ rm,
                      const float* __restrict__ rv,
                      const unsigned short* __restrict__ ws,
                      float* __restrict__ out) {
  __shared__ unsigned short in_h[4 * CGRP];   // 25344 B
  __shared__ unsigned short in_l[4 * CGRP];   // 25344 B

  const int tid = threadIdx.x;
  const int band = blockIdx.x;           // 0..15 -> conv rows 4*band..+3
  const int job = blockIdx.y;            // 0..167
  const bool spiking = job < 160;
  const int r0 = band * 4;

  const float* __restrict__ xin =
      spiking ? (x_st + (size_t)job * IMG) : (x_sc + (size_t)(job - 160) * IMG);

  // ---- Stage: planar fp32 -> c-major NHWC fp16 hi + scaled-lo in LDS ----
  {
    const int col = tid & 63;
    const int g = tid >> 6;              // ci group of 8
    for (int r6 = 0; r6 < 6; ++r6) {
      int row = r0 - 1 + r6;
      float vv[8];
      if ((unsigned)row < 64u) {
        const float* src = xin + (g * 8) * (HWc * HWc) + row * HWc + col;
        #pragma unroll
        for (int jj = 0; jj < 8; ++jj) vv[jj] = src[jj * (HWc * HWc)];
      } else {
        #pragma unroll
        for (int jj = 0; jj < 8; ++jj) vv[jj] = 0.f;
      }
      unsigned int hw[4], lw[4];
      #pragma unroll
      for (int q = 0; q < 4; ++q) {
        float x0 = vv[2 * q], x1 = vv[2 * q + 1];
        _Float16 h0 = (_Float16)x0;
        _Float16 h1 = (_Float16)x1;
        _Float16 l0 = (_Float16)((x0 - (float)h0) * LO_SCALE);
        _Float16 l1 = (_Float16)((x1 - (float)h1) * LO_SCALE);
        hw[q] = (unsigned int)h_bits(h0) | ((unsigned int)h_bits(h1) << 16);
        lw[q] = (unsigned int)h_bits(l0) | ((unsigned int)h_bits(l1) << 16);
      }
      int base = g * CGRP + (r6 * 66 + col + 1) * 8;     // ushort idx, 16B-aligned
      *reinterpret_cast<uint4*>(&in_h[base]) = make_uint4(hw[0], hw[1], hw[2], hw[3]);
      *reinterpret_cast<uint4*>(&in_l[base]) = make_uint4(lw[0], lw[1], lw[2], lw[3]);
    }
    // zero the pad pixel-slots (col -1 and 64) in all 4 ci-groups
    if (tid < 12) {
      int r6 = tid >> 1;
      int slot = (tid & 1) * 65;
      uint4 z = make_uint4(0, 0, 0, 0);
      #pragma unroll
      for (int c = 0; c < 4; ++c) {
        int base = c * CGRP + (r6 * 66 + slot) * 8;
        *reinterpret_cast<uint4*>(&in_h[base]) = z;
        *reinterpret_cast<uint4*>(&in_l[base]) = z;
      }
    }
  }
  __syncthreads();

  // ---- MFMA main loop, two sequential cout-16 halves ----
  const int lane = tid & 63;
  const int wv = tid >> 6;
  const int p = wv & 1;                  // conv-row pair -> pooled row
  const int co0 = (wv >> 1) * 32;        // cout half (32 couts per wave)
  const int laneoff = (lane & 15) * 16 + (lane >> 4) * (CGRP * 2);   // bytes (A)
  const int wlaneoff = (lane & 15) * 64 + (lane >> 4) * 16;           // bytes (B)

  const char* Hbase = (const char*)in_h;
  const char* Lbase = (const char*)in_l;
  const char* WS = (const char*)ws + (spiking ? 0 : 4 * W_ELEMS);  // bytes
  const int WLO = 2 * W_ELEMS;           // byte offset hi->lo

  const int oy = band * 2 + p;

  #pragma unroll 1
  for (int j = 0; j < 2; ++j) {
    f32x4 accH[8];                       // scale-1 accumulator (h*H)
    f32x4 accL[8];                       // scale-2^24 accumulator (h*L' + l'*H)
    #pragma unroll
    for (int m = 0; m < 8; ++m) {
      accH[m] = (f32x4)(0.f);
      accL[m] = (f32x4)(0.f);
    }

    #pragma unroll
    for (int ky = 0; ky < 3; ++ky) {
      #pragma unroll
      for (int kx = 0; kx < 3; ++kx) {
        const int tap = ky * 3 + kx;
        const char* wp = WS + (tap * 64 + co0 + j * 16) * 64 + wlaneoff;
        half8 bh = *reinterpret_cast<const half8*>(wp);
        half8 bl = *reinterpret_cast<const half8*>(wp + WLO);
        #pragma unroll
        for (int m = 0; m < 8; ++m) {
          const int rl = 2 * p + (m >> 2) + ky;          // 0..5
          const int boff = (rl * 66 + (m & 3) * 16 + kx) * 16 + laneoff;
          half8 ah = *reinterpret_cast<const half8*>(Hbase + boff);
          half8 al = *reinterpret_cast<const half8*>(Lbase + boff);
          accH[m] = __builtin_amdgcn_mfma_f32_16x16x32_f16(ah, bh, accH[m], 0, 0, 0);
          accL[m] = __builtin_amdgcn_mfma_f32_16x16x32_f16(al, bh, accL[m], 0, 0, 0);
          accL[m] = __builtin_amdgcn_mfma_f32_16x16x32_f16(ah, bl, accL[m], 0, 0, 0);
        }
      }
    }

    // ---- Epilogue for this cout-16 half: combine scales, pool, bias, store ----
    int co = co0 + j * 16 + (lane & 15);
    float denom = spiking ? sqrtf(rv[co]) : sqrtf(rv[co] + 1e-5f);
    float rs = gamma[co] / denom;
    float beff = (b[co] - rm[co]) * rs + beta[co];
    #pragma unroll
    for (int m = 0; m < 4; ++m) {
      f32x4 tH = accH[m], tL = accL[m];
      f32x4 bH = accH[m + 4], bL = accL[m + 4];
      float t0 = fmaf(LO_INV, tL[0], tH[0]);
      float t1 = fmaf(LO_INV, tL[1], tH[1]);
      float t2 = fmaf(LO_INV, tL[2], tH[2]);
      float t3 = fmaf(LO_INV, tL[3], tH[3]);
      float b0 = fmaf(LO_INV, bL[0], bH[0]);
      float b1 = fmaf(LO_INV, bL[1], bH[1]);
      float b2 = fmaf(LO_INV, bL[2], bH[2]);
      float b3 = fmaf(LO_INV, bL[3], bH[3]);
      float v0 = fmaxf(fmaxf(t0, t1), fmaxf(b0, b1)) + beff;
      float v1 = fmaxf(fmaxf(t2, t3), fmaxf(b2, b3)) + beff;
      int ox = m * 8 + (lane >> 4) * 2;
      if (spiking) {
        float2* dst = reinterpret_cast<float2*>(
            out + (size_t)(job * COUTc + co) * PLANE + oy * OHW + ox);
        *dst = make_float2(v0, v1);
      } else {
        int n = job - 160;
        float2* dst = reinterpret_cast<float2*>(
            out + (size_t)(SPIKE_SZ + CNT_SZ) +
            (size_t)(n * COUTc + co) * PLANE + oy * OHW + ox);
        *dst = make_float2(fmaxf(v0, 0.f), fmaxf(v1, 0.f));
      }
    }
  }
}

// In-place temporal scan: each neuron spikes at most once (mask latches).
__global__ __launch_bounds__(256)
void scan_kernel(float* __restrict__ out) {
  int g = blockIdx.x * 256 + threadIdx.x;    // 0 .. 524287
  int n = g >> 16;
  int rem = g & 65535;
  size_t base = (size_t)n * (T * COUTc * PLANE) + rem;
  float pot = 0.f;
  float spiked = 0.f;
  #pragma unroll
  for (int t = 0; t < T; ++t) {
    size_t idx = base + (size_t)t * (COUTc * PLANE);
    float v = out[idx];
    pot += v;
    float s = (pot >= 1.f && spiked == 0.f) ? 1.f : 0.f;
    out[idx] = s;
    pot -= s;
    spiked = fmaxf(spiked, s);
  }
  out[(size_t)SPIKE_SZ + g] = spiked;
}

extern "C" void kernel_launch(void* const* d_in, const int* in_sizes, int n_in,
                              void* d_out, int out_size, void* d_ws, size_t ws_size,
                              hipStream_t stream) {
  const float* x_st  = (const float*)d_in[0];
  const float* x_sc  = (const float*)d_in[1];
  const float* w     = (const float*)d_in[2];
  const float* b     = (const float*)d_in[3];
  const float* gamma = (const float*)d_in[4];
  const float* beta  = (const float*)d_in[5];
  const float* rm    = (const float*)d_in[6];
  const float* rv    = (const float*)d_in[7];
  float* out = (float*)d_out;
  unsigned short* wsu = (unsigned short*)d_ws;

  wprep_kernel<<<(2 * W_ELEMS + 255) / 256, 256, 0, stream>>>(w, gamma, rv, wsu);
  dim3 grid(16, 168);
  conv_mfma_kernel<<<grid, 256, 0, stream>>>(x_st, x_sc, b, gamma, beta, rm, rv, wsu, out);
  scan_kernel<<<2048, 256, 0, stream>>>(out);
}

// Round 9
// 107.766 us; speedup vs baseline: 4.0201x; 4.0201x over previous
//
#include <hip/hip_runtime.h>

namespace {
constexpr int T = 20;
constexpr int CINc = 32;
constexpr int COUTc = 64;
constexpr int HWc = 64;
constexpr int IMG = CINc * HWc * HWc;            // 131072
constexpr int OHW = 32;
constexpr int PLANE = OHW * OHW;                 // 1024
constexpr int SPIKE_SZ = 8 * T * COUTc * PLANE;  // 10485760
constexpr int CNT_SZ = 8 * COUTc * PLANE;        // 524288
constexpr int W_ELEMS = 9 * COUTc * CINc;        // 18432 per (set, hi/lo)
constexpr float LO_SCALE = 16777216.0f;          // 2^24
constexpr float LO_INV = 5.9604644775390625e-8f; // 2^-24
constexpr int RSTRIDE = 72;                      // pixel slots per staged row (72%8==0)
}

typedef _Float16 half8 __attribute__((ext_vector_type(8)));
typedef float f32x4 __attribute__((ext_vector_type(4)));

__device__ __forceinline__ unsigned short h_bits(_Float16 h) {
  return __builtin_bit_cast(unsigned short, h);
}

// Precompute BN-folded weights in MFMA B-fragment layout, fp16 split:
// w = H + L*2^-24 (L = fp16((w-H)*2^24)).
// ws ushort layout: [set(spike=0,ann=1)][hi=0,lo=1][tap][cout][cin]
__global__ void wprep_kernel(const float* __restrict__ w,
                             const float* __restrict__ gamma,
                             const float* __restrict__ rv,
                             unsigned short* __restrict__ ws) {
  int idx = blockIdx.x * 256 + threadIdx.x;
  if (idx >= 2 * W_ELEMS) return;
  int ci = idx & 31;
  int co = (idx >> 5) & 63;
  int v = idx >> 11;            // 0..17
  int tap = v % 9;
  int set = v / 9;
  float denom = set ? sqrtf(rv[co] + 1e-5f) : sqrtf(rv[co]);
  float val = w[(co * 32 + ci) * 9 + tap] * (gamma[co] / denom);
  _Float16 h = (_Float16)val;
  _Float16 l = (_Float16)((val - (float)h) * LO_SCALE);
  int base = set * (2 * W_ELEMS) + (tap * 64 + co) * 32 + ci;
  ws[base] = h_bits(h);
  ws[base + W_ELEMS] = h_bits(l);
}

// Conv 3x3 pad1 (implicit GEMM via fp16-split MFMA) + BN-fold + 2x2 maxpool.
// Block: 4 conv rows x 64 cols x 64 couts. 4 waves: wave = 2 conv rows x 32 couts.
// LDS: one array of 128B pixel-slots [6 rows][72 slots][8 chunks x 16B]
// (chunks h0..h3,l0..l3), chunk k of pixel p stored at position (k+p)&7.
// Since row stride 72 == 0 (mod 8), pixel&7 = (kx + lane&15)&7 and the A-read
// address is (one of 6) per-lane base regs + compile-time immediate -> the
// rotation spreads 64 lanes uniformly over all 32 banks (8 touches/bank =
// wave64 b128 minimum = conflict-free) while keeping R4's addressing shape.
__global__ __launch_bounds__(256, 2)
void conv_mfma_kernel(const float* __restrict__ x_st,
                      const float* __restrict__ x_sc,
                      const float* __restrict__ b,
                      const float* __restrict__ gamma,
                      const float* __restrict__ beta,
                      const float* __restrict__ rm,
                      const float* __restrict__ rv,
                      const unsigned short* __restrict__ ws,
                      float* __restrict__ out) {
  __shared__ unsigned short in_hl[6 * RSTRIDE * 64];   // 55296 B

  const int tid = threadIdx.x;
  const int band = blockIdx.x;           // 0..15 -> conv rows 4*band..+3
  const int job = blockIdx.y;            // 0..167
  const bool spiking = job < 160;
  const int r0 = band * 4;

  const float* __restrict__ xin =
      spiking ? (x_st + (size_t)job * IMG) : (x_sc + (size_t)(job - 160) * IMG);

  // ---- Stage: planar fp32 -> rotated-chunk NHWC fp16 hi + scaled-lo ----
  {
    const int col = tid & 63;
    const int g = tid >> 6;              // ci group of 8
    const int p = col + 1;               // pixel slot
    const int rot = p & 7;
    const int posH = (g + rot) & 7;
    const int posL = (g + 4 + rot) & 7;
    for (int r6 = 0; r6 < 6; ++r6) {
      int row = r0 - 1 + r6;
      float vv[8];
      if ((unsigned)row < 64u) {
        const float* src = xin + (g * 8) * (HWc * HWc) + row * HWc + col;
        #pragma unroll
        for (int jj = 0; jj < 8; ++jj) vv[jj] = src[jj * (HWc * HWc)];
      } else {
        #pragma unroll
        for (int jj = 0; jj < 8; ++jj) vv[jj] = 0.f;
      }
      unsigned int hw[4], lw[4];
      #pragma unroll
      for (int q = 0; q < 4; ++q) {
        float x0 = vv[2 * q], x1 = vv[2 * q + 1];
        _Float16 h0 = (_Float16)x0;
        _Float16 h1 = (_Float16)x1;
        _Float16 l0 = (_Float16)((x0 - (float)h0) * LO_SCALE);
        _Float16 l1 = (_Float16)((x1 - (float)h1) * LO_SCALE);
        hw[q] = (unsigned int)h_bits(h0) | ((unsigned int)h_bits(h1) << 16);
        lw[q] = (unsigned int)h_bits(l0) | ((unsigned int)h_bits(l1) << 16);
      }
      int sbase = (r6 * RSTRIDE + p) * 64;               // ushort idx of slot
      *reinterpret_cast<uint4*>(&in_hl[sbase + posH * 8]) =
          make_uint4(hw[0], hw[1], hw[2], hw[3]);
      *reinterpret_cast<uint4*>(&in_hl[sbase + posL * 8]) =
          make_uint4(lw[0], lw[1], lw[2], lw[3]);
    }
    // zero the pad pixel-slots 0 and 65 (all 8 chunks -> rotation-invariant)
    if (tid < 12) {
      int r6 = tid >> 1;
      int slot = (tid & 1) * 65;
      int sbase = (r6 * RSTRIDE + slot) * 64;
      uint4 z = make_uint4(0, 0, 0, 0);
      #pragma unroll
      for (int q = 0; q < 8; ++q)
        *reinterpret_cast<uint4*>(&in_hl[sbase + q * 8]) = z;
    }
  }
  __syncthreads();

  // ---- MFMA main loop ----
  const int lane = tid & 63;
  const int wv = tid >> 6;
  const int p = wv & 1;                  // conv-row pair -> pooled row
  const int co0 = (wv >> 1) * 32;        // cout half
  const int s16 = lane & 15;
  const int cg = lane >> 4;              // k-group 0..3
  const int wlaneoff = s16 * 64 + cg * 16;                 // bytes (B frags)

  // Six per-lane A-base offsets (bytes): h and l for each kx.
  int offH[3], offL[3];
  #pragma unroll
  for (int kx = 0; kx < 3; ++kx) {
    offH[kx] = s16 * 128 + ((cg + kx + s16) & 7) * 16;
    offL[kx] = s16 * 128 + ((cg + 4 + kx + s16) & 7) * 16;
  }

  const char* HL = (const char*)in_hl;
  const char* WS = (const char*)ws + (spiking ? 0 : 4 * W_ELEMS);  // bytes
  const int WLO = 2 * W_ELEMS;           // byte offset hi->lo

  f32x4 accH[8][2];                      // scale-1 accumulator (h*H)
  f32x4 accL[8][2];                      // scale-2^24 accumulator (h*L' + l'*H)
  #pragma unroll
  for (int m = 0; m < 8; ++m) {
    accH[m][0] = (f32x4)(0.f);
    accH[m][1] = (f32x4)(0.f);
    accL[m][0] = (f32x4)(0.f);
    accL[m][1] = (f32x4)(0.f);
  }

  #pragma unroll
  for (int ky = 0; ky < 3; ++ky) {
    #pragma unroll
    for (int kx = 0; kx < 3; ++kx) {
      const int tap = ky * 3 + kx;
      const char* wp = WS + (tap * 64 + co0) * 64 + wlaneoff;
      half8 bh0 = *reinterpret_cast<const half8*>(wp);
      half8 bh1 = *reinterpret_cast<const half8*>(wp + 16 * 64);
      half8 bl0 = *reinterpret_cast<const half8*>(wp + WLO);
      half8 bl1 = *reinterpret_cast<const half8*>(wp + WLO + 16 * 64);
      #pragma unroll
      for (int m = 0; m < 8; ++m) {
        const int rl = 2 * p + (m >> 2) + ky;          // 0..5
        const int sb = (rl * RSTRIDE + (m & 3) * 16 + kx) * 128;   // slot base
        half8 ah = *reinterpret_cast<const half8*>(HL + sb + offH[kx]);
        half8 al = *reinterpret_cast<const half8*>(HL + sb + offL[kx]);
        accH[m][0] = __builtin_amdgcn_mfma_f32_16x16x32_f16(ah, bh0, accH[m][0], 0, 0, 0);
        accH[m][1] = __builtin_amdgcn_mfma_f32_16x16x32_f16(ah, bh1, accH[m][1], 0, 0, 0);
        accL[m][0] = __builtin_amdgcn_mfma_f32_16x16x32_f16(al, bh0, accL[m][0], 0, 0, 0);
        accL[m][0] = __builtin_amdgcn_mfma_f32_16x16x32_f16(ah, bl0, accL[m][0], 0, 0, 0);
        accL[m][1] = __builtin_amdgcn_mfma_f32_16x16x32_f16(al, bh1, accL[m][1], 0, 0, 0);
        accL[m][1] = __builtin_amdgcn_mfma_f32_16x16x32_f16(ah, bl1, accL[m][1], 0, 0, 0);
      }
    }
  }

  // ---- Epilogue: combine scales, 2x2 maxpool, bias ----
  const int oy = band * 2 + p;
  #pragma unroll
  for (int j = 0; j < 2; ++j) {
    int co = co0 + j * 16 + s16;
    float denom = spiking ? sqrtf(rv[co]) : sqrtf(rv[co] + 1e-5f);
    float rs = gamma[co] / denom;
    float beff = (b[co] - rm[co]) * rs + beta[co];
    #pragma unroll
    for (int m = 0; m < 4; ++m) {
      f32x4 tH = accH[m][j], tL = accL[m][j];
      f32x4 bH = accH[m + 4][j], bL = accL[m + 4][j];
      float t0 = fmaf(LO_INV, tL[0], tH[0]);
      float t1 = fmaf(LO_INV, tL[1], tH[1]);
      float t2 = fmaf(LO_INV, tL[2], tH[2]);
      float t3 = fmaf(LO_INV, tL[3], tH[3]);
      float b0 = fmaf(LO_INV, bL[0], bH[0]);
      float b1 = fmaf(LO_INV, bL[1], bH[1]);
      float b2 = fmaf(LO_INV, bL[2], bH[2]);
      float b3 = fmaf(LO_INV, bL[3], bH[3]);
      float v0 = fmaxf(fmaxf(t0, t1), fmaxf(b0, b1)) + beff;
      float v1 = fmaxf(fmaxf(t2, t3), fmaxf(b2, b3)) + beff;
      int ox = m * 8 + cg * 2;
      if (spiking) {
        float2* dst = reinterpret_cast<float2*>(
            out + (size_t)(job * COUTc + co) * PLANE + oy * OHW + ox);
        *dst = make_float2(v0, v1);
      } else {
        int n = job - 160;
        float2* dst = reinterpret_cast<float2*>(
            out + (size_t)(SPIKE_SZ + CNT_SZ) +
            (size_t)(n * COUTc + co) * PLANE + oy * OHW + ox);
        *dst = make_float2(fmaxf(v0, 0.f), fmaxf(v1, 0.f));
      }
    }
  }
}

// In-place temporal scan: each neuron spikes at most once (mask latches).
__global__ __launch_bounds__(256)
void scan_kernel(float* __restrict__ out) {
  int g = blockIdx.x * 256 + threadIdx.x;    // 0 .. 524287
  int n = g >> 16;
  int rem = g & 65535;
  size_t base = (size_t)n * (T * COUTc * PLANE) + rem;
  float pot = 0.f;
  float spiked = 0.f;
  #pragma unroll
  for (int t = 0; t < T; ++t) {
    size_t idx = base + (size_t)t * (COUTc * PLANE);
    float v = out[idx];
    pot += v;
    float s = (pot >= 1.f && spiked == 0.f) ? 1.f : 0.f;
    out[idx] = s;
    pot -= s;
    spiked = fmaxf(spiked, s);
  }
  out[(size_t)SPIKE_SZ + g] = spiked;
}

extern "C" void kernel_launch(void* const* d_in, const int* in_sizes, int n_in,
                              void* d_out, int out_size, void* d_ws, size_t ws_size,
                              hipStream_t stream) {
  const float* x_st  = (const float*)d_in[0];
  const float* x_sc  = (const float*)d_in[1];
  const float* w     = (const float*)d_in[2];
  const float* b     = (const float*)d_in[3];
  const float* gamma = (const float*)d_in[4];
  const float* beta  = (const float*)d_in[5];
  const float* rm    = (const float*)d_in[6];
  const float* rv    = (const float*)d_in[7];
  float* out = (float*)d_out;
  unsigned short* wsu = (unsigned short*)d_ws;

  wprep_kernel<<<(2 * W_ELEMS + 255) / 256, 256, 0, stream>>>(w, gamma, rv, wsu);
  dim3 grid(16, 168);
  conv_mfma_kernel<<<grid, 256, 0, stream>>>(x_st, x_sc, b, gamma, beta, rm, rv, wsu, out);
  scan_kernel<<<2048, 256, 0, stream>>>(out);
}

// Round 10
// 104.909 us; speedup vs baseline: 4.1296x; 1.0272x over previous
//
#include <hip/hip_runtime.h>

namespace {
constexpr int T = 20;
constexpr int CINc = 32;
constexpr int COUTc = 64;
constexpr int HWc = 64;
constexpr int IMG = CINc * HWc * HWc;            // 131072
constexpr int OHW = 32;
constexpr int PLANE = OHW * OHW;                 // 1024
constexpr int SPIKE_SZ = 8 * T * COUTc * PLANE;  // 10485760
constexpr int CNT_SZ = 8 * COUTc * PLANE;        // 524288
constexpr int W_ELEMS = 9 * COUTc * CINc;        // 18432 per (set, hi/lo)
constexpr float LO_SCALE = 16777216.0f;          // 2^24
constexpr float LO_INV = 5.9604644775390625e-8f; // 2^-24
}

typedef _Float16 half8 __attribute__((ext_vector_type(8)));
typedef float f32x4 __attribute__((ext_vector_type(4)));

__device__ __forceinline__ unsigned short h_bits(_Float16 h) {
  return __builtin_bit_cast(unsigned short, h);
}

// Precompute BN-folded weights in MFMA B-fragment layout, fp16 split:
// w = H + L*2^-24 (L = fp16((w-H)*2^24)).
// ws ushort layout: [set(spike=0,ann=1)][hi=0,lo=1][tap][cout][cin]
__global__ void wprep_kernel(const float* __restrict__ w,
                             const float* __restrict__ gamma,
                             const float* __restrict__ rv,
                             unsigned short* __restrict__ ws) {
  int idx = blockIdx.x * 256 + threadIdx.x;
  if (idx >= 2 * W_ELEMS) return;
  int ci = idx & 31;
  int co = (idx >> 5) & 63;
  int v = idx >> 11;            // 0..17
  int tap = v % 9;
  int set = v / 9;
  float denom = set ? sqrtf(rv[co] + 1e-5f) : sqrtf(rv[co]);
  float val = w[(co * 32 + ci) * 9 + tap] * (gamma[co] / denom);
  _Float16 h = (_Float16)val;
  _Float16 l = (_Float16)((val - (float)h) * LO_SCALE);
  int base = set * (2 * W_ELEMS) + (tap * 64 + co) * 32 + ci;
  ws[base] = h_bits(h);
  ws[base + W_ELEMS] = h_bits(l);
}

// Conv 3x3 pad1 (implicit GEMM via fp16-split MFMA) + BN-fold + 2x2 maxpool.
// Block: 4 conv rows x 64 cols x 64 couts. 4 waves: wave = 2 conv rows x 32 couts.
// R4 structure with chunk rotation: chunk g of pixel-slot p is stored at
// position (g + 2p)&3 within the slot (16B granularity). Read offset then
// depends only on kx PARITY: offA_even / offA_odd = offA_even^32 -> only +2
// address regs vs R4, while A ds_read_b128 lanes spread over all 8 bank
// quads (8 lanes each = wave64 minimum = conflict-free).
__global__ __launch_bounds__(256, 2)
void conv_mfma_kernel(const float* __restrict__ x_st,
                      const float* __restrict__ x_sc,
                      const float* __restrict__ b,
                      const float* __restrict__ gamma,
                      const float* __restrict__ beta,
                      const float* __restrict__ rm,
                      const float* __restrict__ rv,
                      const unsigned short* __restrict__ ws,
                      float* __restrict__ out) {
  // NHWC fp16 tiles: [6 rows][66 col-slots (slot0/65 = zero pad)][32 ci]
  __shared__ unsigned short in_h[6 * 66 * 32];
  __shared__ unsigned short in_l[6 * 66 * 32];

  const int tid = threadIdx.x;
  const int band = blockIdx.x;           // 0..15 -> conv rows 4*band..+3
  const int job = blockIdx.y;            // 0..167
  const bool spiking = job < 160;
  const int r0 = band * 4;

  const float* __restrict__ xin =
      spiking ? (x_st + (size_t)job * IMG) : (x_sc + (size_t)(job - 160) * IMG);

  // ---- Stage: planar fp32 -> NHWC fp16 hi + scaled-lo in LDS (rotated) ----
  {
    const int col = tid & 63;
    const int g = tid >> 6;              // ci group of 8
    const int pos = (g + 2 * ((col + 1) & 1)) & 3;   // chunk position in slot
    for (int r6 = 0; r6 < 6; ++r6) {
      int row = r0 - 1 + r6;
      float vv[8];
      if ((unsigned)row < 64u) {
        const float* src = xin + (g * 8) * (HWc * HWc) + row * HWc + col;
        #pragma unroll
        for (int jj = 0; jj < 8; ++jj) vv[jj] = src[jj * (HWc * HWc)];
      } else {
        #pragma unroll
        for (int jj = 0; jj < 8; ++jj) vv[jj] = 0.f;
      }
      unsigned int hw[4], lw[4];
      #pragma unroll
      for (int q = 0; q < 4; ++q) {
        float x0 = vv[2 * q], x1 = vv[2 * q + 1];
        _Float16 h0 = (_Float16)x0;
        _Float16 h1 = (_Float16)x1;
        _Float16 l0 = (_Float16)((x0 - (float)h0) * LO_SCALE);
        _Float16 l1 = (_Float16)((x1 - (float)h1) * LO_SCALE);
        hw[q] = (unsigned int)h_bits(h0) | ((unsigned int)h_bits(h1) << 16);
        lw[q] = (unsigned int)h_bits(l0) | ((unsigned int)h_bits(l1) << 16);
      }
      int base = (r6 * 66 + col + 1) * 32 + pos * 8;   // ushort index, %8==0
      *reinterpret_cast<uint4*>(&in_h[base]) = make_uint4(hw[0], hw[1], hw[2], hw[3]);
      *reinterpret_cast<uint4*>(&in_l[base]) = make_uint4(lw[0], lw[1], lw[2], lw[3]);
    }
    // zero the pad col-slots 0 and 65 (all 4 chunks -> rotation-invariant)
    if (tid < 12) {
      int r6 = tid >> 1;
      int slot = (tid & 1) * 65;
      int base = (r6 * 66 + slot) * 32;
      uint4 z = make_uint4(0, 0, 0, 0);
      #pragma unroll
      for (int q = 0; q < 4; ++q) {
        *reinterpret_cast<uint4*>(&in_h[base + q * 8]) = z;
        *reinterpret_cast<uint4*>(&in_l[base + q * 8]) = z;
      }
    }
  }
  __syncthreads();

  // ---- MFMA main loop ----
  const int lane = tid & 63;
  const int wv = tid >> 6;
  const int p = wv & 1;                  // conv-row pair -> pooled row
  const int co0 = (wv >> 1) * 32;        // cout half
  const int s16 = lane & 15;
  const int cg = lane >> 4;
  const int wlaneoff = s16 * 64 + cg * 16;                   // bytes (B frags)
  // A-fragment lane offsets: slot = (even) + kx + s16, rotation (cg+2*slot)&3.
  const int offA0 = s16 * 64 + (((cg + 2 * (s16 & 1)) & 3)) * 16;  // kx even
  const int offA1 = offA0 ^ 32;                                     // kx odd

  const char* Hbase = (const char*)in_h;
  const char* Lbase = (const char*)in_l;
  const char* HbE = Hbase + offA0;
  const char* HbO = Hbase + offA1;
  const char* LbE = Lbase + offA0;
  const char* LbO = Lbase + offA1;
  const char* WS = (const char*)ws + (spiking ? 0 : 4 * W_ELEMS);  // bytes
  const int WLO = 2 * W_ELEMS;           // byte offset hi->lo

  f32x4 accH[8][2];                      // scale-1 accumulator (h*H)
  f32x4 accL[8][2];                      // scale-2^24 accumulator (h*L' + l'*H)
  #pragma unroll
  for (int m = 0; m < 8; ++m) {
    accH[m][0] = (f32x4)(0.f);
    accH[m][1] = (f32x4)(0.f);
    accL[m][0] = (f32x4)(0.f);
    accL[m][1] = (f32x4)(0.f);
  }

  #pragma unroll
  for (int ky = 0; ky < 3; ++ky) {
    #pragma unroll
    for (int kx = 0; kx < 3; ++kx) {
      const int tap = ky * 3 + kx;
      const char* wp = WS + (tap * 64 + co0) * 64 + wlaneoff;
      half8 bh0 = *reinterpret_cast<const half8*>(wp);
      half8 bh1 = *reinterpret_cast<const half8*>(wp + 16 * 64);
      half8 bl0 = *reinterpret_cast<const half8*>(wp + WLO);
      half8 bl1 = *reinterpret_cast<const half8*>(wp + WLO + 16 * 64);
      const char* Hb = (kx & 1) ? HbO : HbE;
      const char* Lb = (kx & 1) ? LbO : LbE;
      #pragma unroll
      for (int m = 0; m < 8; ++m) {
        const int rl = 2 * p + (m >> 2) + ky;          // 0..5
        const int boff = (rl * 66 + (m & 3) * 16 + kx) * 64;
        half8 ah = *reinterpret_cast<const half8*>(Hb + boff);
        half8 al = *reinterpret_cast<const half8*>(Lb + boff);
        accH[m][0] = __builtin_amdgcn_mfma_f32_16x16x32_f16(ah, bh0, accH[m][0], 0, 0, 0);
        accH[m][1] = __builtin_amdgcn_mfma_f32_16x16x32_f16(ah, bh1, accH[m][1], 0, 0, 0);
        accL[m][0] = __builtin_amdgcn_mfma_f32_16x16x32_f16(al, bh0, accL[m][0], 0, 0, 0);
        accL[m][0] = __builtin_amdgcn_mfma_f32_16x16x32_f16(ah, bl0, accL[m][0], 0, 0, 0);
        accL[m][1] = __builtin_amdgcn_mfma_f32_16x16x32_f16(al, bh1, accL[m][1], 0, 0, 0);
        accL[m][1] = __builtin_amdgcn_mfma_f32_16x16x32_f16(ah, bl1, accL[m][1], 0, 0, 0);
      }
    }
  }

  // ---- Epilogue: combine scales, 2x2 maxpool, bias ----
  const int oy = band * 2 + p;
  #pragma unroll
  for (int j = 0; j < 2; ++j) {
    int co = co0 + j * 16 + s16;
    float denom = spiking ? sqrtf(rv[co]) : sqrtf(rv[co] + 1e-5f);
    float rs = gamma[co] / denom;
    float beff = (b[co] - rm[co]) * rs + beta[co];
    #pragma unroll
    for (int m = 0; m < 4; ++m) {
      f32x4 tH = accH[m][j], tL = accL[m][j];
      f32x4 bH = accH[m + 4][j], bL = accL[m + 4][j];
      float t0 = fmaf(LO_INV, tL[0], tH[0]);
      float t1 = fmaf(LO_INV, tL[1], tH[1]);
      float t2 = fmaf(LO_INV, tL[2], tH[2]);
      float t3 = fmaf(LO_INV, tL[3], tH[3]);
      float b0 = fmaf(LO_INV, bL[0], bH[0]);
      float b1 = fmaf(LO_INV, bL[1], bH[1]);
      float b2 = fmaf(LO_INV, bL[2], bH[2]);
      float b3 = fmaf(LO_INV, bL[3], bH[3]);
      float v0 = fmaxf(fmaxf(t0, t1), fmaxf(b0, b1)) + beff;
      float v1 = fmaxf(fmaxf(t2, t3), fmaxf(b2, b3)) + beff;
      int ox = m * 8 + cg * 2;
      if (spiking) {
        float2* dst = reinterpret_cast<float2*>(
            out + (size_t)(job * COUTc + co) * PLANE + oy * OHW + ox);
        *dst = make_float2(v0, v1);
      } else {
        int n = job - 160;
        float2* dst = reinterpret_cast<float2*>(
            out + (size_t)(SPIKE_SZ + CNT_SZ) +
            (size_t)(n * COUTc + co) * PLANE + oy * OHW + ox);
        *dst = make_float2(fmaxf(v0, 0.f), fmaxf(v1, 0.f));
      }
    }
  }
}

// In-place temporal scan: each neuron spikes at most once (mask latches).
__global__ __launch_bounds__(256)
void scan_kernel(float* __restrict__ out) {
  int g = blockIdx.x * 256 + threadIdx.x;    // 0 .. 524287
  int n = g >> 16;
  int rem = g & 65535;
  size_t base = (size_t)n * (T * COUTc * PLANE) + rem;
  float pot = 0.f;
  float spiked = 0.f;
  #pragma unroll
  for (int t = 0; t < T; ++t) {
    size_t idx = base + (size_t)t * (COUTc * PLANE);
    float v = out[idx];
    pot += v;
    float s = (pot >= 1.f && spiked == 0.f) ? 1.f : 0.f;
    out[idx] = s;
    pot -= s;
    spiked = fmaxf(spiked, s);
  }
  out[(size_t)SPIKE_SZ + g] = spiked;
}

extern "C" void kernel_launch(void* const* d_in, const int* in_sizes, int n_in,
                              void* d_out, int out_size, void* d_ws, size_t ws_size,
                              hipStream_t stream) {
  const float* x_st  = (const float*)d_in[0];
  const float* x_sc  = (const float*)d_in[1];
  const float* w     = (const float*)d_in[2];
  const float* b     = (const float*)d_in[3];
  const float* gamma = (const float*)d_in[4];
  const float* beta  = (const float*)d_in[5];
  const float* rm    = (const float*)d_in[6];
  const float* rv    = (const float*)d_in[7];
  float* out = (float*)d_out;
  unsigned short* wsu = (unsigned short*)d_ws;

  wprep_kernel<<<(2 * W_ELEMS + 255) / 256, 256, 0, stream>>>(w, gamma, rv, wsu);
  dim3 grid(16, 168);
  conv_mfma_kernel<<<grid, 256, 0, stream>>>(x_st, x_sc, b, gamma, beta, rm, rv, wsu, out);
  scan_kernel<<<2048, 256, 0, stream>>>(out);
}